// Round 6
// baseline (278.845 us; speedup 1.0000x reference)
//
#include <hip/hip_runtime.h>
#include <hip/hip_bf16.h>

#define F_IN  512
#define F_HID 16
#define F_OUT 40
#define CH    8192   // edges per workgroup in bucket pass

typedef __attribute__((ext_vector_type(4))) float f32x4;
typedef __attribute__((ext_vector_type(8))) short s16x8;
typedef unsigned short ushort_t;
typedef unsigned int uint_t;

__device__ __forceinline__ float lof(uint_t v) { return __uint_as_float(v << 16); }
__device__ __forceinline__ float hif(uint_t v) { return __uint_as_float(v & 0xffff0000u); }
__device__ __forceinline__ ushort_t f2bf(float f) {
    __hip_bfloat16 h = __float2bfloat16(f);   // RNE
    union { __hip_bfloat16 h; ushort_t u; } v; v.h = h; return v.u;
}

// ---------------- fused: xw1 (raw h1, bf16 MFMA) + bucket histogram ----------------
// blocks [0, nbX): one 16-row tile per wave (8 waves/block), h1 = bf16(x @ W1) UNSCALED
// blocks [nbX, nbX+NWGE): per-block bucket histograms of col (bucket = col>>9)
__global__ __launch_bounds__(512) void k_pre(const float* __restrict__ x,
                                             const float* __restrict__ W1,
                                             ushort_t* __restrict__ g1b,
                                             const int* __restrict__ col,
                                             int* __restrict__ bhall,
                                             int n_tiles, int nbX, int nE) {
    __shared__ int bh[256];
    int t = threadIdx.x;
    if ((int)blockIdx.x < nbX) {
        int lane = t & 63;
        int wid  = t >> 6;
        int m = lane & 15;
        int g = lane >> 4;
        int tile = blockIdx.x * 8 + wid;
        if (tile >= n_tiles) return;

        s16x8 bf[16];
#pragma unroll
        for (int kb = 0; kb < 16; ++kb) {
            union { s16x8 s; unsigned u[4]; } bu;
#pragma unroll
            for (int p = 0; p < 4; ++p) {
                int k0 = kb * 32 + g * 8 + p * 2;
                float lo = W1[(k0 + 0) * F_HID + m];
                float hi = W1[(k0 + 1) * F_HID + m];
                unsigned pk;
                asm("v_cvt_pk_bf16_f32 %0, %1, %2" : "=v"(pk) : "v"(lo), "v"(hi));
                bu.u[p] = pk;
            }
            bf[kb] = bu.s;
        }

        const float* xr = x + (size_t)(tile * 16 + m) * F_IN + g * 8;
        f32x4 acc = {0.f, 0.f, 0.f, 0.f};
#pragma unroll
        for (int kb = 0; kb < 16; ++kb) {
            f32x4 xa = *(const f32x4*)(xr + kb * 32);
            f32x4 xb = *(const f32x4*)(xr + kb * 32 + 4);
            union { s16x8 s; unsigned u[4]; } au;
            asm("v_cvt_pk_bf16_f32 %0, %1, %2" : "=v"(au.u[0]) : "v"(xa.x), "v"(xa.y));
            asm("v_cvt_pk_bf16_f32 %0, %1, %2" : "=v"(au.u[1]) : "v"(xa.z), "v"(xa.w));
            asm("v_cvt_pk_bf16_f32 %0, %1, %2" : "=v"(au.u[2]) : "v"(xb.x), "v"(xb.y));
            asm("v_cvt_pk_bf16_f32 %0, %1, %2" : "=v"(au.u[3]) : "v"(xb.z), "v"(xb.w));
            acc = __builtin_amdgcn_mfma_f32_16x16x32_bf16(au.s, bf[kb], acc, 0, 0, 0);
        }
#pragma unroll
        for (int p = 0; p < 4; ++p) {
            int rr = tile * 16 + g * 4 + p;
            g1b[(size_t)rr * F_HID + m] = f2bf(acc[p]);   // raw, dinv applied in k_build
        }
    } else {
        int b = blockIdx.x - nbX;
        if (t < 256) bh[t] = 0;
        __syncthreads();
        int base = b * CH;
        int end  = min(base + CH, nE);
        for (int e = base + t; e < end; e += 512)
            atomicAdd(&bh[col[e] >> 9], 1);
        __syncthreads();
        if (t < 256) bhall[b * 256 + t] = bh[t];
    }
}

// column-sum the per-block histograms (coalesced) then exclusive-scan
__global__ void k_bscan2(const int* __restrict__ bhall, int* __restrict__ bstart,
                         int* __restrict__ bcur, int nwge) {
    __shared__ int s[256];
    int t = threadIdx.x;
    int sum = 0;
    for (int w = 0; w < nwge; ++w) sum += bhall[w * 256 + t];
    s[t] = sum;
    __syncthreads();
    for (int off = 1; off < 256; off <<= 1) {
        int v = (t >= off) ? s[t - off] : 0;
        __syncthreads();
        s[t] += v;
        __syncthreads();
    }
    int ex = s[t] - sum;
    bstart[t] = ex;
    bcur[t] = ex;
    if (t == 255) bstart[256] = s[255];
}

// scatter packed (row<<9 | col_local) into bucket-contiguous regions
__global__ __launch_bounds__(1024) void k_bscatter(const int* __restrict__ row,
                                                   const int* __restrict__ colv,
                                                   int* __restrict__ bcur,
                                                   int* __restrict__ pairs, int nE) {
    __shared__ int colS[CH];
    __shared__ int bh[256];
    __shared__ int lcur[256];
    int t = threadIdx.x;
    if (t < 256) bh[t] = 0;
    __syncthreads();
    int base = blockIdx.x * CH;
    int end  = min(base + CH, nE);
    for (int e = base + t; e < end; e += 1024) {
        int c = colv[e];
        colS[e - base] = c;
        atomicAdd(&bh[c >> 9], 1);
    }
    __syncthreads();
    if (t < 256) {
        int v = bh[t];
        if (v) lcur[t] = atomicAdd(&bcur[t], v);
    }
    __syncthreads();
    for (int e = base + t; e < end; e += 1024) {
        int c = colS[e - base];
        int pos = atomicAdd(&lcur[c >> 9], 1);
        pairs[pos] = (row[e] << 9) | (c & 511);
    }
}

// one block per bucket: LDS node-histogram -> LDS scan -> start/dinv writes ->
// in-place dinv rescale of this bucket's g1 rows -> LDS-cursor fine scatter.
__global__ __launch_bounds__(1024) void k_build(const int* __restrict__ bstart,
                                                const int* __restrict__ pairs,
                                                int* __restrict__ start,
                                                int* __restrict__ csr,
                                                float* __restrict__ dinv,
                                                uint_t* __restrict__ g1,
                                                int n, int nE) {
    __shared__ int h[512];
    __shared__ int s[512];
    __shared__ int cur[512];
    __shared__ float dv[512];
    int t = threadIdx.x;
    if (t < 512) h[t] = 0;
    __syncthreads();
    int s0 = bstart[blockIdx.x], s1 = bstart[blockIdx.x + 1];
    for (int e = s0 + t; e < s1; e += 1024)
        atomicAdd(&h[pairs[e] & 511], 1);
    __syncthreads();
    if (t < 512) s[t] = h[t];
    __syncthreads();
    for (int off = 1; off < 512; off <<= 1) {
        int v = 0;
        if (t < 512 && t >= off) v = s[t - off];
        __syncthreads();
        if (t < 512) s[t] += v;
        __syncthreads();
    }
    int nbase = blockIdx.x << 9;
    if (t < 512) {
        int c = h[t];
        int st = s0 + s[t] - c;
        int node = nbase + t;
        float d = rsqrtf((float)c + 1.0f);
        if (node < n) { start[node] = st; dinv[node] = d; }
        dv[t] = d;
        cur[t] = st;
    }
    if (blockIdx.x == 0 && t == 0) start[n] = nE;
    __syncthreads();
    // in-place rescale: g1[node] *= dinv[node]  (each thread: half a row = 4 dwords)
    {
        int nl = t >> 1;
        int node = nbase + nl;
        if (node < n) {
            float d = dv[nl];
            uint_t* gp = g1 + (size_t)node * 8 + (t & 1) * 4;
#pragma unroll
            for (int i = 0; i < 4; ++i) {
                uint_t v = gp[i];
                float lo = lof(v) * d, hi = hif(v) * d;
                unsigned pk;
                asm("v_cvt_pk_bf16_f32 %0, %1, %2" : "=v"(pk) : "v"(lo), "v"(hi));
                gp[i] = pk;
            }
        }
    }
    // fine scatter (no sync needed: uses cur via LDS atomics, disjoint from rescale)
    for (int e = s0 + t; e < s1; e += 1024) {
        int v = pairs[e];
        int pos = atomicAdd(&cur[v & 511], 1);
        csr[pos] = v >> 9;
    }
}

// ---------------- gather layer 1 (grid-stride, contiguous node chunks per wave) ----------------
// g2 = bf16( dinv * relu( dinv*(g1[self] + sum g1[in]) + b1 ) ), g1 pre-scaled by dinv[src]
__global__ __launch_bounds__(256) void k_gather1(const int* __restrict__ start,
                                                 const int* __restrict__ csr,
                                                 const uint_t* __restrict__ g1,
                                                 const float* __restrict__ dinv,
                                                 const float* __restrict__ b1,
                                                 uint_t* __restrict__ g2, int n, int npw) {
    int gw = (blockIdx.x * 256 + threadIdx.x) >> 6;
    int lane = threadIdx.x & 63;
    int fp = lane & 7, sub = lane >> 3;
    int n0 = gw * npw, n1 = min(n0 + npw, n);
    if (n0 >= n) return;
    float2 bb = ((const float2*)b1)[fp];
    int sA = start[n0];
    for (int node = n0; node < n1; ++node) {
        int sB = start[node + 1];
        int len = sB - sA;
        int q = (len + 7) >> 3;
        int e = sA + sub * q;
        int end = min(e + q, sB);
        float l0 = 0.f, h0 = 0.f, l1 = 0.f, h1 = 0.f, l2 = 0.f, h2 = 0.f, l3 = 0.f, h3 = 0.f;
        for (; e + 4 <= end; e += 4) {
            int r0 = csr[e], r1 = csr[e + 1], r2 = csr[e + 2], r3 = csr[e + 3];
            uint_t v0 = g1[r0 * 8 + fp], v1 = g1[r1 * 8 + fp];
            uint_t v2 = g1[r2 * 8 + fp], v3 = g1[r3 * 8 + fp];
            l0 += lof(v0); h0 += hif(v0);
            l1 += lof(v1); h1 += hif(v1);
            l2 += lof(v2); h2 += hif(v2);
            l3 += lof(v3); h3 += hif(v3);
        }
        for (; e < end; ++e) {
            uint_t v = g1[csr[e] * 8 + fp];
            l0 += lof(v); h0 += hif(v);
        }
        float alo = (l0 + l1) + (l2 + l3);
        float ahi = (h0 + h1) + (h2 + h3);
        alo += __shfl_xor(alo, 8);  ahi += __shfl_xor(ahi, 8);
        alo += __shfl_xor(alo, 16); ahi += __shfl_xor(ahi, 16);
        alo += __shfl_xor(alo, 32); ahi += __shfl_xor(ahi, 32);
        uint_t sv = g1[(size_t)node * 8 + fp];     // self-loop (already dinv-scaled)
        alo += lof(sv); ahi += hif(sv);
        float di = dinv[node];
        float hlo = fmaxf(di * alo + bb.x, 0.f) * di;
        float hhi = fmaxf(di * ahi + bb.y, 0.f) * di;
        if (sub == 0) {
            unsigned pk;
            asm("v_cvt_pk_bf16_f32 %0, %1, %2" : "=v"(pk) : "v"(hlo), "v"(hhi));
            g2[(size_t)node * 8 + fp] = pk;
        }
        sA = sB;
    }
}

// ---------------- gather layer 2 fused with W2 + bias + log_softmax ----------------
__global__ __launch_bounds__(256) void k_gather2f(const int* __restrict__ start,
                                                  const int* __restrict__ csr,
                                                  const uint_t* __restrict__ g2,
                                                  const float* __restrict__ dinv,
                                                  const float* __restrict__ W2,
                                                  const float* __restrict__ b2,
                                                  float* __restrict__ out, int n, int npw) {
    int gw = (blockIdx.x * 256 + threadIdx.x) >> 6;
    int lane = threadIdx.x & 63;
    int fp = lane & 7, sub = lane >> 3;
    int n0 = gw * npw, n1 = min(n0 + npw, n);
    if (n0 >= n) return;
    int j = (lane < F_OUT) ? lane : 0;
    float w2c[F_HID];
#pragma unroll
    for (int k = 0; k < F_HID; ++k) w2c[k] = W2[k * F_OUT + j];
    float bj = b2[j];

    int sA = start[n0];
    for (int node = n0; node < n1; ++node) {
        int sB = start[node + 1];
        int len = sB - sA;
        int q = (len + 7) >> 3;
        int e = sA + sub * q;
        int end = min(e + q, sB);
        float l0 = 0.f, h0 = 0.f, l1 = 0.f, h1 = 0.f, l2 = 0.f, h2 = 0.f, l3 = 0.f, h3 = 0.f;
        for (; e + 4 <= end; e += 4) {
            int r0 = csr[e], r1 = csr[e + 1], r2 = csr[e + 2], r3 = csr[e + 3];
            uint_t v0 = g2[r0 * 8 + fp], v1 = g2[r1 * 8 + fp];
            uint_t v2 = g2[r2 * 8 + fp], v3 = g2[r3 * 8 + fp];
            l0 += lof(v0); h0 += hif(v0);
            l1 += lof(v1); h1 += hif(v1);
            l2 += lof(v2); h2 += hif(v2);
            l3 += lof(v3); h3 += hif(v3);
        }
        for (; e < end; ++e) {
            uint_t v = g2[csr[e] * 8 + fp];
            l0 += lof(v); h0 += hif(v);
        }
        float alo = (l0 + l1) + (l2 + l3);
        float ahi = (h0 + h1) + (h2 + h3);
        alo += __shfl_xor(alo, 8);  ahi += __shfl_xor(ahi, 8);
        alo += __shfl_xor(alo, 16); ahi += __shfl_xor(ahi, 16);
        alo += __shfl_xor(alo, 32); ahi += __shfl_xor(ahi, 32);
        uint_t sv = g2[(size_t)node * 8 + fp];     // self-loop
        alo += lof(sv); ahi += hif(sv);
        float di = dinv[node];
        float a_lo = di * alo;   // a[2*fp]
        float a_hi = di * ahi;   // a[2*fp+1]

        float o = bj;
#pragma unroll
        for (int k = 0; k < F_HID; k += 2) {
            o += __shfl(a_lo, k >> 1) * w2c[k] + __shfl(a_hi, k >> 1) * w2c[k + 1];
        }

        float mo = (lane < F_OUT) ? o : -3.4e38f;
#pragma unroll
        for (int off = 32; off; off >>= 1) mo = fmaxf(mo, __shfl_xor(mo, off));
        float ev = (lane < F_OUT) ? __expf(o - mo) : 0.f;
        float sv2 = ev;
#pragma unroll
        for (int off = 32; off; off >>= 1) sv2 += __shfl_xor(sv2, off);
        float lse = mo + __logf(sv2);
        if (lane < F_OUT) out[(size_t)node * F_OUT + lane] = o - lse;
        sA = sB;
    }
}

// ---------------- launcher ----------------

extern "C" void kernel_launch(void* const* d_in, const int* in_sizes, int n_in,
                              void* d_out, int out_size, void* d_ws, size_t ws_size,
                              hipStream_t stream) {
    const float* x  = (const float*)d_in[0];
    const int*   ei = (const int*)d_in[1];
    const float* W1 = (const float*)d_in[2];
    const float* b1 = (const float*)d_in[3];
    const float* W2 = (const float*)d_in[4];
    const float* b2 = (const float*)d_in[5];
    float* out = (float*)d_out;

    const int N = out_size / F_OUT;       // 100000
    const int E = in_sizes[1] / 2;        // 3200000
    const int* row = ei;                  // sources
    const int* col = ei + E;              // targets

    const int NBUCK = (N + 511) >> 9;     // 196
    const int NWGE  = (E + CH - 1) / CH;  // 391
    const int tiles = (N + 15) / 16;      // 6250
    const int nbX   = (tiles + 7) / 8;    // 782 (8 tiles/block, 512t)
    const int GBLK  = 2048;               // gather blocks (8192 waves)
    const int npw   = (N + GBLK * 4 - 1) / (GBLK * 4);   // nodes per wave

    // workspace layout
    int* bstart   = (int*)d_ws;                 // 260 (NBUCK+1 used)
    int* bcur     = bstart + 260;               // 256
    int* bhall    = bcur + 256;                 // NWGE*256
    int* start    = bhall + NWGE * 256;         // N+4
    int* csr      = start + N + 4;              // E
    int* pairs    = csr + E;                    // E
    float* dinv   = (float*)(pairs + E);        // N
    uint_t* g1    = (uint_t*)(dinv + N);        // 8N dwords (bf16x2 rows)
    uint_t* g2    = g1 + (size_t)N * 8;         // 8N dwords

    k_pre<<<nbX + NWGE, 512, 0, stream>>>(x, W1, (ushort_t*)g1, col, bhall, tiles, nbX, E);
    k_bscan2<<<1, 256, 0, stream>>>(bhall, bstart, bcur, NWGE);
    k_bscatter<<<NWGE, 1024, 0, stream>>>(row, col, bcur, pairs, E);
    k_build<<<NBUCK, 1024, 0, stream>>>(bstart, pairs, start, csr, dinv, g1, N, E);

    k_gather1<<<GBLK, 256, 0, stream>>>(start, csr, g1, dinv, b1, g2, N, npw);
    k_gather2f<<<GBLK, 256, 0, stream>>>(start, csr, g2, dinv, W2, b2, out, N, npw);
}